// Round 7
// baseline (271.695 us; speedup 1.0000x reference)
//
#include <hip/hip_runtime.h>
#include <hip/hip_bf16.h>

typedef __bf16 bf16;
typedef __bf16 bf16x8 __attribute__((ext_vector_type(8)));
typedef __bf16 bf16x4 __attribute__((ext_vector_type(4)));
typedef float f32x4 __attribute__((ext_vector_type(4)));

#define MFMA16(a, b, c) __builtin_amdgcn_mfma_f32_16x16x32_bf16((a), (b), (c), 0, 0, 0)

constexpr int LQ = 2048, LK = 4096, E = 512, H = 8, DH = 64;
// q pre-scale: 1/sqrt(DH) * log2(e) folded into the q-projection epilogue
#define QSCALE 0.1803368801111137f

__device__ __forceinline__ bf16x8 ld8(const bf16* p) { return *(const bf16x8*)p; }

// ------------- fp32 -> bf16 conversion of the 4 weight matrices ------------
__global__ __launch_bounds__(256) void cvt4_kernel(
    const float* __restrict__ w0, const float* __restrict__ w1,
    const float* __restrict__ w2, const float* __restrict__ w3,
    bf16* __restrict__ dst) {
  const float* srcs[4] = {w0, w1, w2, w3};
  const float* src = srcs[blockIdx.y];
  bf16* d = dst + (size_t)blockIdx.y * 262144;
  int i = (blockIdx.x * 256 + threadIdx.x) * 4;
  f32x4 v = *(const f32x4*)(src + i);
  bf16x4 o;
  for (int j = 0; j < 4; ++j) o[j] = (bf16)v[j];
  *(bf16x4*)(d + i) = o;
}

// ------------- q/k/v projection, LDS-staged GEMM --------------------------
// C[128x128] per block, 4 waves 2x2 of 64x64, BK=64. q output pre-scaled by
// QSCALE so attention softmax is a bare exp2.
__global__ __launch_bounds__(256) void proj_gemm_kernel(
    const float* __restrict__ query, const float* __restrict__ kv,
    const bf16* __restrict__ Wall,
    const float* __restrict__ bq, const float* __restrict__ bk,
    const float* __restrict__ bv,
    bf16* __restrict__ qproj, bf16* __restrict__ kproj, bf16* __restrict__ vt) {
  __shared__ bf16 sm[2][128][72];
  const int tid = threadIdx.x;
  const int lane = tid & 63, wave = tid >> 6;
  const int lrow = lane & 15, quad = lane >> 4;
  const int wm = wave & 1, wn = wave >> 1;

  int x = blockIdx.x, z, mt;
  if (x < 32) { z = 0; mt = x; }
  else if (x < 96) { z = 1; mt = x - 32; }
  else { z = 2; mt = x - 96; }
  const float* A = ((z == 0) ? query : kv) + (size_t)mt * 128 * E;
  const bf16* W = Wall + (size_t)z * 262144;
  const float* bias = (z == 0) ? bq : (z == 1) ? bk : bv;
  const int n0 = blockIdx.y * 128;

  const int sr = tid >> 1, sh = tid & 1;
  const float* ga = A + (size_t)sr * E + sh * 32;
  const bf16* gb = W + (size_t)(n0 + sr) * E + sh * 32;

  f32x4 pa[8];
  bf16x8 pb[4];
  for (int j = 0; j < 8; ++j) pa[j] = *(const f32x4*)(ga + j * 4);
  for (int j = 0; j < 4; ++j) pb[j] = ld8(gb + j * 8);

  f32x4 acc[4][4] = {};
  for (int t = 0; t < 8; ++t) {
    for (int j = 0; j < 4; ++j) {
      bf16x8 av;
      for (int e = 0; e < 4; ++e) {
        av[e] = (bf16)pa[2 * j][e];
        av[e + 4] = (bf16)pa[2 * j + 1][e];
      }
      *(bf16x8*)&sm[0][sr][sh * 32 + j * 8] = av;
      *(bf16x8*)&sm[1][sr][sh * 32 + j * 8] = pb[j];
    }
    __syncthreads();

    if (t < 7) {
      const float* ga2 = ga + (t + 1) * 64;
      const bf16* gb2 = gb + (t + 1) * 64;
      for (int j = 0; j < 8; ++j) pa[j] = *(const f32x4*)(ga2 + j * 4);
      for (int j = 0; j < 4; ++j) pb[j] = ld8(gb2 + j * 8);
    }

    bf16x8 af[2][4], bfr[2][4];
    for (int ks = 0; ks < 2; ++ks)
      for (int i = 0; i < 4; ++i)
        af[ks][i] = ld8(&sm[0][wm * 64 + 16 * i + lrow][ks * 32 + quad * 8]);
    for (int ks = 0; ks < 2; ++ks)
      for (int c = 0; c < 4; ++c)
        bfr[ks][c] = ld8(&sm[1][wn * 64 + 16 * c + lrow][ks * 32 + quad * 8]);
    for (int ks = 0; ks < 2; ++ks)
      for (int i = 0; i < 4; ++i)
        for (int c = 0; c < 4; ++c)
          acc[i][c] = MFMA16(af[ks][i], bfr[ks][c], acc[i][c]);
    __syncthreads();
  }

  const float qsc = (z == 0) ? QSCALE : 1.f;
  float bvl[4];
  for (int c = 0; c < 4; ++c) bvl[c] = bias[n0 + wn * 64 + 16 * c + lrow];
  bf16* Cs = &sm[0][0][0];  // reuse as [128][136]
  for (int i = 0; i < 4; ++i)
    for (int c = 0; c < 4; ++c)
      for (int r = 0; r < 4; ++r) {
        int row = wm * 64 + 16 * i + 4 * quad + r;
        int col = wn * 64 + 16 * c + lrow;
        bf16 val = (bf16)((acc[i][c][r] + bvl[c]) * qsc);
        if (z < 2) Cs[row * 136 + col] = val;
        else       Cs[col * 136 + row] = val;
      }
  __syncthreads();
  const int rr = tid >> 1, hh = tid & 1;
  if (z < 2) {
    bf16* Y = (z == 0) ? qproj : kproj;
    bf16* dstp = Y + (size_t)(mt * 128 + rr) * E + n0 + hh * 64;
    for (int j = 0; j < 8; ++j)
      *(bf16x8*)(dstp + j * 8) = *(bf16x8*)&Cs[rr * 136 + hh * 64 + j * 8];
  } else {
    int m0g = mt * 128, b = m0g >> 12, kk0 = m0g & 4095;
    int ng = n0 + rr, hd = ng >> 6, d = ng & 63;
    bf16* dstp = vt + ((size_t)((b * 8 + hd) * 64 + d)) * LK + kk0 + hh * 64;
    for (int j = 0; j < 8; ++j)
      *(bf16x8*)(dstp + j * 8) = *(bf16x8*)&Cs[rr * 136 + hh * 64 + j * 8];
  }
}

// ---------------- fused flash attention v4: barrier-free -------------------
// K/V fragments loaded DIRECTLY from global (L2-hot: 512 KB per head slice,
// reused by 32 blocks) with 1-iter register prefetch. Only P round-trips
// through LDS (wave-private -> NO __syncthreads in the 64-iter loop).
// Softmax = bare exp2 (q pre-scaled in proj). Max-free (|s|<~9 << 127).
// 4 waves = 2 q-subtiles (32 q) x 2 kk-halves (2048 kk); combine at end.
// grid = 512 (2 blocks/CU), block 256.
__global__ __launch_bounds__(256, 2) void attn_kernel(
    const bf16* __restrict__ qp, const bf16* __restrict__ kp,
    const bf16* __restrict__ vtg, bf16* __restrict__ ctx) {
  const int tid = threadIdx.x;
  const int lane = tid & 63, wave = tid >> 6;
  const int lrow = lane & 15, quad = lane >> 4;
  const int blk = blockIdx.x;
  const int qt = blk & 31, bh = blk >> 5;
  const int b = bh >> 3, h = bh & 7;
  const int wq = wave & 1, half = wave >> 1;
  const int q0 = qt * 64 + wq * 32;

  __shared__ bf16 Ps[4][32][40];    // per-wave P [q][kk]
  __shared__ float F[2][32][65];    // half-1 partial O for combine
  __shared__ float Lr[2][2][16];    // half-1 partial row sums

  bf16x8 qf[2][2];  // [g][sd]; q pre-scaled by QSCALE in proj
  for (int g = 0; g < 2; ++g)
    for (int s = 0; s < 2; ++s)
      qf[g][s] = ld8(qp + (size_t)(b * LQ + q0 + 16 * g + lrow) * E + h * DH +
                     32 * s + quad * 8);

  float lrun[2] = {0.f, 0.f};
  f32x4 acc[2][4] = {};

  // per-lane global fragment bases (A-layout for K, B-layout for V^T)
  const bf16* kfb =
      kp + ((size_t)(b * LK) + half * 2048 + lrow) * E + h * DH + quad * 8;
  const bf16* vfb =
      vtg + ((size_t)(bh * DH) + lrow) * LK + half * 2048 + quad * 8;

  bf16x8 kf[2][2], vf[4], nkf[2][2], nvf[4];
  for (int kt = 0; kt < 2; ++kt)
    for (int sd = 0; sd < 2; ++sd)
      kf[kt][sd] = ld8(kfb + (size_t)(16 * kt) * E + 32 * sd);
  for (int c = 0; c < 4; ++c)
    vf[c] = ld8(vfb + (size_t)(16 * c) * LK);

  for (int it = 0; it < 64; ++it) {
    if (it < 63) {  // prefetch next 32-kk fragment set
      const bf16* kn = kfb + (size_t)(it + 1) * 32 * E;
      const bf16* vn = vfb + (it + 1) * 32;
      for (int kt = 0; kt < 2; ++kt)
        for (int sd = 0; sd < 2; ++sd)
          nkf[kt][sd] = ld8(kn + (size_t)(16 * kt) * E + 32 * sd);
      for (int c = 0; c < 4; ++c)
        nvf[c] = ld8(vn + (size_t)(16 * c) * LK);
    }

    // S^T = K Q^T: lane q = lrow (+16g), kk = 16kt + 4quad + r
    f32x4 st[2][2];
    for (int g = 0; g < 2; ++g)
      for (int kt = 0; kt < 2; ++kt) {
        st[g][kt] = (f32x4){0.f, 0.f, 0.f, 0.f};
        st[g][kt] = MFMA16(kf[kt][0], qf[g][0], st[g][kt]);
        st[g][kt] = MFMA16(kf[kt][1], qf[g][1], st[g][kt]);
      }
    // p = 2^st (scale folded into q); packed 8B stores, wave-private LDS
    for (int g = 0; g < 2; ++g)
      for (int kt = 0; kt < 2; ++kt) {
        bf16x4 pp;
        for (int r = 0; r < 4; ++r) {
          float p = exp2f(st[g][kt][r]);
          lrun[g] += p;
          pp[r] = (bf16)p;
        }
        *(bf16x4*)&Ps[wave][16 * g + lrow][16 * kt + 4 * quad] = pp;
      }
    // PV: A = P rows (q, 32 kk contiguous), B = V^T rows (d)
    for (int g = 0; g < 2; ++g) {
      bf16x8 pf = ld8(&Ps[wave][16 * g + lrow][quad * 8]);
      for (int c = 0; c < 4; ++c)
        acc[g][c] = MFMA16(pf, vf[c], acc[g][c]);
    }
    for (int kt = 0; kt < 2; ++kt)
      for (int sd = 0; sd < 2; ++sd) kf[kt][sd] = nkf[kt][sd];
    for (int c = 0; c < 4; ++c) vf[c] = nvf[c];
  }

  // full partial row sums within each half (all lanes get sum for q = lrow)
  for (int g = 0; g < 2; ++g) {
    lrun[g] += __shfl_xor(lrun[g], 16);
    lrun[g] += __shfl_xor(lrun[g], 32);
  }

  // combine halves: half 1 publishes partial O + row sums, half 0 merges
  __syncthreads();
  if (half == 1) {
    for (int g = 0; g < 2; ++g)
      for (int c = 0; c < 4; ++c)
        for (int r = 0; r < 4; ++r)
          F[wq][16 * g + 4 * quad + r][16 * c + lrow] = acc[g][c][r];
    if (lane < 16)
      for (int g = 0; g < 2; ++g) Lr[wq][g][lrow] = lrun[g];
  }
  __syncthreads();
  if (half == 0) {
    for (int g = 0; g < 2; ++g)
      for (int r = 0; r < 4; ++r) {
        float l0 = __shfl(lrun[g], 4 * quad + r);
        float l1 = Lr[wq][g][4 * quad + r];
        float inv = 1.f / (l0 + l1);
        int m = q0 + 16 * g + 4 * quad + r;
        bf16* dst = ctx + (size_t)(b * LQ + m) * E + h * DH;
        for (int c = 0; c < 4; ++c) {
          float o = acc[g][c][r] + F[wq][16 * g + 4 * quad + r][16 * c + lrow];
          dst[16 * c + lrow] = (bf16)(o * inv);
        }
      }
  }
}

// ------- out-proj + bias + residual + LayerNorm (Wo reg-prefetch) ----------
__global__ __launch_bounds__(512) void outln_kernel(
    const bf16* __restrict__ Cx, const bf16* __restrict__ Wo,
    const float* __restrict__ bo, const float* __restrict__ resid,
    const float* __restrict__ gamma, const float* __restrict__ beta,
    float* __restrict__ out) {
  const int tid = threadIdx.x;
  const int lane = tid & 63, wave = tid >> 6;
  const int lrow = lane & 15, quad = lane >> 4;
  const int m0 = blockIdx.x * 16;
  const int n0 = wave * 64;

  __shared__ bf16 As[16][520];
  __shared__ float red1[16][8], red2[16][8];
  {
    int r = tid >> 5, ch = tid & 31;
    const bf16* src = Cx + (size_t)(m0 + r) * E + ch * 16;
    *(bf16x8*)&As[r][ch * 16] = ld8(src);
    *(bf16x8*)&As[r][ch * 16 + 8] = ld8(src + 8);
  }
  __syncthreads();

  f32x4 acc[4] = {};
  const bf16* wbase = Wo + (size_t)(n0 + lrow) * E + quad * 8;
  bf16x8 wreg[4];
  for (int c = 0; c < 4; ++c) wreg[c] = ld8(wbase + (size_t)(16 * c) * E);
  for (int k0 = 0; k0 < E; k0 += 32) {
    bf16x8 cur[4];
    for (int c = 0; c < 4; ++c) cur[c] = wreg[c];
    if (k0 + 32 < E)
      for (int c = 0; c < 4; ++c)
        wreg[c] = ld8(wbase + (size_t)(16 * c) * E + k0 + 32);
    bf16x8 a = *(const bf16x8*)&As[lrow][k0 + quad * 8];
    for (int c = 0; c < 4; ++c) acc[c] = MFMA16(a, cur[c], acc[c]);
  }
  float s1[4] = {}, s2[4] = {};
  for (int c = 0; c < 4; ++c) {
    int n = n0 + 16 * c + lrow;
    float bb = bo[n];
    for (int r = 0; r < 4; ++r) {
      int m = 4 * quad + r;
      float xv = acc[c][r] + bb + resid[(size_t)(m0 + m) * E + n];
      acc[c][r] = xv;
      s1[r] += xv;
      s2[r] += xv * xv;
    }
  }
  for (int off = 1; off < 16; off <<= 1)
    for (int r = 0; r < 4; ++r) {
      s1[r] += __shfl_xor(s1[r], off);
      s2[r] += __shfl_xor(s2[r], off);
    }
  if (lrow == 0)
    for (int r = 0; r < 4; ++r) {
      red1[4 * quad + r][wave] = s1[r];
      red2[4 * quad + r][wave] = s2[r];
    }
  __syncthreads();
  float mu[4], rstd[4];
  for (int r = 0; r < 4; ++r) {
    int m = 4 * quad + r;
    float t1 = 0.f, t2 = 0.f;
    for (int w = 0; w < 8; ++w) { t1 += red1[m][w]; t2 += red2[m][w]; }
    float mean = t1 * (1.f / 512.f);
    float var = t2 * (1.f / 512.f) - mean * mean;
    mu[r] = mean;
    rstd[r] = rsqrtf(var + 1e-5f);
  }
  for (int c = 0; c < 4; ++c) {
    int n = n0 + 16 * c + lrow;
    float gm = gamma[n], bt = beta[n];
    for (int r = 0; r < 4; ++r) {
      int m = m0 + 4 * quad + r;
      out[(size_t)m * E + n] = (acc[c][r] - mu[r]) * rstd[r] * gm + bt;
    }
  }
}

extern "C" void kernel_launch(void* const* d_in, const int* in_sizes, int n_in,
                              void* d_out, int out_size, void* d_ws, size_t ws_size,
                              hipStream_t stream) {
  const float* query     = (const float*)d_in[0];
  const float* key_value = (const float*)d_in[1];
  const float* Wq = (const float*)d_in[2];
  const float* bq = (const float*)d_in[3];
  const float* Wk = (const float*)d_in[4];
  const float* bk = (const float*)d_in[5];
  const float* Wv = (const float*)d_in[6];
  const float* bv = (const float*)d_in[7];
  const float* Wo = (const float*)d_in[8];
  const float* bo = (const float*)d_in[9];
  const float* gamma = (const float*)d_in[10];
  const float* beta  = (const float*)d_in[11];
  float* out = (float*)d_out;

  // ws layout (bf16): 4 weights | qproj(=ctx alias) | kproj | vt  (23 MB)
  bf16* Wb    = (bf16*)d_ws;
  bf16* Wob   = Wb + (size_t)3 * 262144;
  bf16* qproj = Wb + (size_t)4 * 262144;
  bf16* kproj = qproj + (size_t)4096 * 512;
  bf16* vt    = kproj + (size_t)8192 * 512;

  cvt4_kernel<<<dim3(256, 4), 256, 0, stream>>>(Wq, Wk, Wv, Wo, Wb);
  proj_gemm_kernel<<<dim3(160, 4), 256, 0, stream>>>(
      query, key_value, Wb, bq, bk, bv, qproj, kproj, vt);
  attn_kernel<<<512, 256, 0, stream>>>(qproj, kproj, vt, qproj /*ctx in-place*/);
  outln_kernel<<<256, 512, 0, stream>>>(qproj, Wob, bo, query, gamma, beta, out);
}

// Round 8
// 204.401 us; speedup vs baseline: 1.3292x; 1.3292x over previous
//
#include <hip/hip_runtime.h>
#include <hip/hip_bf16.h>

typedef __bf16 bf16;
typedef __bf16 bf16x8 __attribute__((ext_vector_type(8)));
typedef __bf16 bf16x4 __attribute__((ext_vector_type(4)));
typedef float f32x4 __attribute__((ext_vector_type(4)));

#define MFMA16(a, b, c) __builtin_amdgcn_mfma_f32_16x16x32_bf16((a), (b), (c), 0, 0, 0)

constexpr int LQ = 2048, LK = 4096, E = 512, H = 8, DH = 64;
// q pre-scale: 1/sqrt(DH) * log2(e) folded into q-projection epilogue
#define QSCALE 0.1803368801111137f

__device__ __forceinline__ bf16x8 ld8(const bf16* p) { return *(const bf16x8*)p; }

// ------------- fp32 -> bf16 conversion of the 4 weight matrices ------------
__global__ __launch_bounds__(256) void cvt4_kernel(
    const float* __restrict__ w0, const float* __restrict__ w1,
    const float* __restrict__ w2, const float* __restrict__ w3,
    bf16* __restrict__ dst) {
  const float* srcs[4] = {w0, w1, w2, w3};
  const float* src = srcs[blockIdx.y];
  bf16* d = dst + (size_t)blockIdx.y * 262144;
  int i = (blockIdx.x * 256 + threadIdx.x) * 4;
  f32x4 v = *(const f32x4*)(src + i);
  bf16x4 o;
  for (int j = 0; j < 4; ++j) o[j] = (bf16)v[j];
  *(bf16x4*)(d + i) = o;
}

// ------------- q/k/v projection, LDS-staged GEMM, COALESCED staging -------
// C[128x128] per block, 4 waves 2x2 of 64x64, BK=64 (8 k-tiles).
// Staging maps: consecutive lanes -> consecutive 16B chunks (min transactions).
// q output pre-scaled by QSCALE so attention softmax is a bare exp2.
__global__ __launch_bounds__(256) void proj_gemm_kernel(
    const float* __restrict__ query, const float* __restrict__ kv,
    const bf16* __restrict__ Wall,
    const float* __restrict__ bq, const float* __restrict__ bk,
    const float* __restrict__ bv,
    bf16* __restrict__ qproj, bf16* __restrict__ kproj, bf16* __restrict__ vt) {
  __shared__ bf16 sm[2][128][72];
  const int tid = threadIdx.x;
  const int lane = tid & 63, wave = tid >> 6;
  const int lrow = lane & 15, quad = lane >> 4;
  const int wm = wave & 1, wn = wave >> 1;

  int x = blockIdx.x, z, mt;
  if (x < 32) { z = 0; mt = x; }
  else if (x < 96) { z = 1; mt = x - 32; }
  else { z = 2; mt = x - 96; }
  const float* A = ((z == 0) ? query : kv) + (size_t)mt * 128 * E;
  const bf16* W = Wall + (size_t)z * 262144;
  const float* bias = (z == 0) ? bq : (z == 1) ? bk : bv;
  const int n0 = blockIdx.y * 128;

  // A: 128 rows x 64 fp32; chunk = 4 fp32 (16B). row = p*16 + tid/16.
  const int arow = tid >> 4, acol = tid & 15;
  // B: 128 rows x 64 bf16; chunk = 8 bf16 (16B). row = p*32 + tid/8.
  const int brow = tid >> 3, bcol = tid & 7;

  f32x4 pa[8];
  bf16x8 pb[4];
  for (int p = 0; p < 8; ++p)
    pa[p] = *(const f32x4*)(A + (size_t)(p * 16 + arow) * E + acol * 4);
  for (int p = 0; p < 4; ++p)
    pb[p] = ld8(W + (size_t)(n0 + p * 32 + brow) * E + bcol * 8);

  f32x4 acc[4][4] = {};
  for (int t = 0; t < 8; ++t) {
    for (int p = 0; p < 8; ++p) {
      bf16x4 av;
      for (int e = 0; e < 4; ++e) av[e] = (bf16)pa[p][e];
      *(bf16x4*)&sm[0][p * 16 + arow][acol * 4] = av;
    }
    for (int p = 0; p < 4; ++p)
      *(bf16x8*)&sm[1][p * 32 + brow][bcol * 8] = pb[p];
    __syncthreads();

    if (t < 7) {  // prefetch next k-tile (coalesced)
      const float* ga2 = A + (t + 1) * 64;
      const bf16* gb2 = W + (t + 1) * 64;
      for (int p = 0; p < 8; ++p)
        pa[p] = *(const f32x4*)(ga2 + (size_t)(p * 16 + arow) * E + acol * 4);
      for (int p = 0; p < 4; ++p)
        pb[p] = ld8(gb2 + (size_t)(n0 + p * 32 + brow) * E + bcol * 8);
    }

    bf16x8 af[2][4], bfr[2][4];
    for (int ks = 0; ks < 2; ++ks)
      for (int i = 0; i < 4; ++i)
        af[ks][i] = ld8(&sm[0][wm * 64 + 16 * i + lrow][ks * 32 + quad * 8]);
    for (int ks = 0; ks < 2; ++ks)
      for (int c = 0; c < 4; ++c)
        bfr[ks][c] = ld8(&sm[1][wn * 64 + 16 * c + lrow][ks * 32 + quad * 8]);
    for (int ks = 0; ks < 2; ++ks)
      for (int i = 0; i < 4; ++i)
        for (int c = 0; c < 4; ++c)
          acc[i][c] = MFMA16(af[ks][i], bfr[ks][c], acc[i][c]);
    __syncthreads();
  }

  const float qsc = (z == 0) ? QSCALE : 1.f;
  float bvl[4];
  for (int c = 0; c < 4; ++c) bvl[c] = bias[n0 + wn * 64 + 16 * c + lrow];
  bf16* Cs = &sm[0][0][0];  // reuse as [128][136]
  for (int i = 0; i < 4; ++i)
    for (int c = 0; c < 4; ++c)
      for (int r = 0; r < 4; ++r) {
        int row = wm * 64 + 16 * i + 4 * quad + r;
        int col = wn * 64 + 16 * c + lrow;
        bf16 val = (bf16)((acc[i][c][r] + bvl[c]) * qsc);
        if (z < 2) Cs[row * 136 + col] = val;
        else       Cs[col * 136 + row] = val;
      }
  __syncthreads();
  const int rr = tid >> 1, hh = tid & 1;
  if (z < 2) {
    bf16* Y = (z == 0) ? qproj : kproj;
    bf16* dstp = Y + (size_t)(mt * 128 + rr) * E + n0 + hh * 64;
    for (int j = 0; j < 8; ++j)
      *(bf16x8*)(dstp + j * 8) = *(bf16x8*)&Cs[rr * 136 + hh * 64 + j * 8];
  } else {
    int m0g = mt * 128, b = m0g >> 12, kk0 = m0g & 4095;
    int ng = n0 + rr, hd = ng >> 6, d = ng & 63;
    bf16* dstp = vt + ((size_t)((b * 8 + hd) * 64 + d)) * LK + kk0 + hh * 64;
    for (int j = 0; j < 8; ++j)
      *(bf16x8*)(dstp + j * 8) = *(bf16x8*)&Cs[rr * 136 + hh * 64 + j * 8];
  }
}

// ---------------- fused flash attention v3 (r6 revert, exp2 softmax) -------
// 4 waves = 2 q-subtiles (32 q each) x 2 kk-halves (2048 kk each).
// LDS-staged K/V (coalesced), double-buffered, 1 barrier/iter. Max-free
// softmax = bare exp2 (q pre-scaled by QSCALE in proj). ctx in-place.
// grid = 512 (2 blocks/CU), block 256.
__global__ __launch_bounds__(256, 2) void attn_kernel(
    const bf16* __restrict__ qp, const bf16* __restrict__ kp,
    const bf16* __restrict__ vtg, bf16* __restrict__ ctx) {
  const int tid = threadIdx.x;
  const int lane = tid & 63, wave = tid >> 6;
  const int lrow = lane & 15, quad = lane >> 4;
  const int blk = blockIdx.x;
  const int qt = blk & 31, bh = blk >> 5;
  const int b = bh >> 3, h = bh & 7;
  const int wq = wave & 1, half = wave >> 1;
  const int q0 = qt * 64 + wq * 32;

  __shared__ bf16 Ks[2][2][32][72];   // [half][dbuf][kk][d]
  __shared__ bf16 Vs[2][2][64][40];   // [half][dbuf][d][kk]
  __shared__ bf16 Ps[4][32][40];      // per-wave P [q][kk]
  __shared__ float Lr[2][2][16];      // half-1 row sums [wq][g][q]

  bf16x8 qf[2][2];  // [g][sd]; q pre-scaled by QSCALE
  for (int g = 0; g < 2; ++g)
    for (int s = 0; s < 2; ++s)
      qf[g][s] = ld8(qp + (size_t)(b * LQ + q0 + 16 * g + lrow) * E + h * DH +
                     32 * s + quad * 8);

  float lrun[2] = {0.f, 0.f};
  f32x4 acc[2][4] = {};

  // staging within the 128-thread half-group
  const int th = tid & 127;
  const int krow = th >> 2, kch = th & 3;  // K: 32 kk-rows x 4 d-chunks
  const int vrow = th >> 1, vch = th & 1;  // V: 64 d-rows x 2 kk-chunks
  const bf16* kbase =
      kp + ((size_t)(b * LK) + half * 2048 + krow) * E + h * DH + kch * 16;
  const bf16* vbase =
      vtg + ((size_t)bh * DH + vrow) * LK + half * 2048 + vch * 16;

  bf16x8 pk0 = ld8(kbase), pk1 = ld8(kbase + 8);
  bf16x8 pv0 = ld8(vbase), pv1 = ld8(vbase + 8);

  for (int it = 0; it < 64; ++it) {
    const int bs = it & 1;
    *(bf16x8*)&Ks[half][bs][krow][kch * 16] = pk0;
    *(bf16x8*)&Ks[half][bs][krow][kch * 16 + 8] = pk1;
    *(bf16x8*)&Vs[half][bs][vrow][vch * 16] = pv0;
    *(bf16x8*)&Vs[half][bs][vrow][vch * 16 + 8] = pv1;
    __syncthreads();

    if (it < 63) {  // prefetch next 32-kk tile
      const bf16* kn = kbase + (size_t)(it + 1) * 32 * E;
      const bf16* vn = vbase + (it + 1) * 32;
      pk0 = ld8(kn); pk1 = ld8(kn + 8);
      pv0 = ld8(vn); pv1 = ld8(vn + 8);
    }

    bf16x8 kf[2][2], vf[4];
    for (int kt = 0; kt < 2; ++kt)
      for (int sd = 0; sd < 2; ++sd)
        kf[kt][sd] = ld8(&Ks[half][bs][16 * kt + lrow][32 * sd + quad * 8]);
    for (int c = 0; c < 4; ++c)
      vf[c] = ld8(&Vs[half][bs][16 * c + lrow][quad * 8]);

    // S^T = K Q^T: lane q = lrow (+16g), kk = 16kt + 4quad + r
    f32x4 st[2][2];
    for (int g = 0; g < 2; ++g)
      for (int kt = 0; kt < 2; ++kt) {
        st[g][kt] = (f32x4){0.f, 0.f, 0.f, 0.f};
        st[g][kt] = MFMA16(kf[kt][0], qf[g][0], st[g][kt]);
        st[g][kt] = MFMA16(kf[kt][1], qf[g][1], st[g][kt]);
      }
    for (int g = 0; g < 2; ++g)
      for (int kt = 0; kt < 2; ++kt) {
        bf16x4 pp;
        for (int r = 0; r < 4; ++r) {
          float p = exp2f(st[g][kt][r]);
          lrun[g] += p;
          pp[r] = (bf16)p;
        }
        *(bf16x4*)&Ps[wave][16 * g + lrow][16 * kt + 4 * quad] = pp;
      }
    // PV: A = P rows (q), k = kk 32; B = V^T rows (d)
    for (int g = 0; g < 2; ++g) {
      bf16x8 pf = ld8(&Ps[wave][16 * g + lrow][quad * 8]);
      for (int c = 0; c < 4; ++c)
        acc[g][c] = MFMA16(pf, vf[c], acc[g][c]);
    }
  }

  // full partial row sums within each half
  for (int g = 0; g < 2; ++g) {
    lrun[g] += __shfl_xor(lrun[g], 16);
    lrun[g] += __shfl_xor(lrun[g], 32);
  }

  // combine halves: half 1 publishes partial O + row sums, half 0 merges
  __syncthreads();
  float* F = (float*)&Ks[0][0][0][0];  // [2][32][65] floats
  if (half == 1) {
    for (int g = 0; g < 2; ++g)
      for (int c = 0; c < 4; ++c)
        for (int r = 0; r < 4; ++r)
          F[(wq * 32 + 16 * g + 4 * quad + r) * 65 + 16 * c + lrow] =
              acc[g][c][r];
    if (lane < 16)
      for (int g = 0; g < 2; ++g) Lr[wq][g][lrow] = lrun[g];
  }
  __syncthreads();
  if (half == 0) {
    for (int g = 0; g < 2; ++g)
      for (int r = 0; r < 4; ++r) {
        float l0 = __shfl(lrun[g], 4 * quad + r);
        float l1 = Lr[wq][g][4 * quad + r];
        float inv = 1.f / (l0 + l1);
        int m = q0 + 16 * g + 4 * quad + r;
        bf16* dst = ctx + (size_t)(b * LQ + m) * E + h * DH;
        for (int c = 0; c < 4; ++c) {
          float o = acc[g][c][r] +
                    F[(wq * 32 + 16 * g + 4 * quad + r) * 65 + 16 * c + lrow];
          dst[16 * c + lrow] = (bf16)(o * inv);
        }
      }
  }
}

// ------- out-proj + bias + residual + LayerNorm; Wo LDS-staged -------------
// Block 512 thr: 16 m-rows x full N=512 (wave w: n in [64w,64w+64)).
// Wo staged in 64-k tiles (coalesced 128B row-chunks, 1-tile prefetch).
__global__ __launch_bounds__(512) void outln_kernel(
    const bf16* __restrict__ Cx, const bf16* __restrict__ Wo,
    const float* __restrict__ bo, const float* __restrict__ resid,
    const float* __restrict__ gamma, const float* __restrict__ beta,
    float* __restrict__ out) {
  const int tid = threadIdx.x;
  const int lane = tid & 63, wave = tid >> 6;
  const int lrow = lane & 15, quad = lane >> 4;
  const int m0 = blockIdx.x * 16;
  const int n0 = wave * 64;

  __shared__ bf16 As[16][520];
  __shared__ bf16 Wos[512][72];
  __shared__ float red1[16][8], red2[16][8];
  {
    int r = tid >> 5, ch = tid & 31;
    const bf16* src = Cx + (size_t)(m0 + r) * E + ch * 16;
    *(bf16x8*)&As[r][ch * 16] = ld8(src);
    *(bf16x8*)&As[r][ch * 16 + 8] = ld8(src + 8);
  }
  // Wo staging map: row = p*64 + tid/8, chunk = tid&7 (8x16B = 128B/row)
  const int wr = tid >> 3, wc = tid & 7;
  bf16x8 pw[8];
  for (int p = 0; p < 8; ++p)
    pw[p] = ld8(Wo + (size_t)(p * 64 + wr) * E + wc * 8);
  __syncthreads();  // As ready

  f32x4 acc[4] = {};
  for (int t = 0; t < 8; ++t) {
    for (int p = 0; p < 8; ++p)
      *(bf16x8*)&Wos[p * 64 + wr][wc * 8] = pw[p];
    __syncthreads();
    if (t < 7)
      for (int p = 0; p < 8; ++p)
        pw[p] = ld8(Wo + (size_t)(p * 64 + wr) * E + (t + 1) * 64 + wc * 8);
    for (int ks = 0; ks < 2; ++ks) {
      bf16x8 a = *(const bf16x8*)&As[lrow][t * 64 + ks * 32 + quad * 8];
      for (int c = 0; c < 4; ++c) {
        bf16x8 w = *(const bf16x8*)&Wos[n0 + 16 * c + lrow][ks * 32 + quad * 8];
        acc[c] = MFMA16(a, w, acc[c]);
      }
    }
    __syncthreads();
  }

  float s1[4] = {}, s2[4] = {};
  for (int c = 0; c < 4; ++c) {
    int n = n0 + 16 * c + lrow;
    float bb = bo[n];
    for (int r = 0; r < 4; ++r) {
      int m = 4 * quad + r;
      float xv = acc[c][r] + bb + resid[(size_t)(m0 + m) * E + n];
      acc[c][r] = xv;
      s1[r] += xv;
      s2[r] += xv * xv;
    }
  }
  for (int off = 1; off < 16; off <<= 1)
    for (int r = 0; r < 4; ++r) {
      s1[r] += __shfl_xor(s1[r], off);
      s2[r] += __shfl_xor(s2[r], off);
    }
  if (lrow == 0)
    for (int r = 0; r < 4; ++r) {
      red1[4 * quad + r][wave] = s1[r];
      red2[4 * quad + r][wave] = s2[r];
    }
  __syncthreads();
  float mu[4], rstd[4];
  for (int r = 0; r < 4; ++r) {
    int m = 4 * quad + r;
    float t1 = 0.f, t2 = 0.f;
    for (int w = 0; w < 8; ++w) { t1 += red1[m][w]; t2 += red2[m][w]; }
    float mean = t1 * (1.f / 512.f);
    float var = t2 * (1.f / 512.f) - mean * mean;
    mu[r] = mean;
    rstd[r] = rsqrtf(var + 1e-5f);
  }
  for (int c = 0; c < 4; ++c) {
    int n = n0 + 16 * c + lrow;
    float gm = gamma[n], bt = beta[n];
    for (int r = 0; r < 4; ++r) {
      int m = m0 + 4 * quad + r;
      out[(size_t)m * E + n] = (acc[c][r] - mu[r]) * rstd[r] * gm + bt;
    }
  }
}

extern "C" void kernel_launch(void* const* d_in, const int* in_sizes, int n_in,
                              void* d_out, int out_size, void* d_ws, size_t ws_size,
                              hipStream_t stream) {
  const float* query     = (const float*)d_in[0];
  const float* key_value = (const float*)d_in[1];
  const float* Wq = (const float*)d_in[2];
  const float* bq = (const float*)d_in[3];
  const float* Wk = (const float*)d_in[4];
  const float* bk = (const float*)d_in[5];
  const float* Wv = (const float*)d_in[6];
  const float* bv = (const float*)d_in[7];
  const float* Wo = (const float*)d_in[8];
  const float* bo = (const float*)d_in[9];
  const float* gamma = (const float*)d_in[10];
  const float* beta  = (const float*)d_in[11];
  float* out = (float*)d_out;

  // ws layout (bf16): 4 weights | qproj(=ctx alias) | kproj | vt  (23 MB)
  bf16* Wb    = (bf16*)d_ws;
  bf16* Wob   = Wb + (size_t)3 * 262144;
  bf16* qproj = Wb + (size_t)4 * 262144;
  bf16* kproj = qproj + (size_t)4096 * 512;
  bf16* vt    = kproj + (size_t)8192 * 512;

  cvt4_kernel<<<dim3(256, 4), 256, 0, stream>>>(Wq, Wk, Wv, Wo, Wb);
  proj_gemm_kernel<<<dim3(160, 4), 256, 0, stream>>>(
      query, key_value, Wb, bq, bk, bv, qproj, kproj, vt);
  attn_kernel<<<512, 256, 0, stream>>>(qproj, kproj, vt, qproj /*ctx in-place*/);
  outln_kernel<<<256, 512, 0, stream>>>(qproj, Wob, bo, query, gamma, beta, out);
}

// Round 9
// 191.425 us; speedup vs baseline: 1.4193x; 1.0678x over previous
//
#include <hip/hip_runtime.h>
#include <hip/hip_bf16.h>

typedef __bf16 bf16;
typedef __bf16 bf16x8 __attribute__((ext_vector_type(8)));
typedef __bf16 bf16x4 __attribute__((ext_vector_type(4)));
typedef float f32x4 __attribute__((ext_vector_type(4)));

#define MFMA16(a, b, c) __builtin_amdgcn_mfma_f32_16x16x32_bf16((a), (b), (c), 0, 0, 0)

constexpr int LQ = 2048, LK = 4096, E = 512, H = 8, DH = 64;
// q pre-scale: 1/sqrt(DH) * log2(e) folded into q-projection epilogue
#define QSCALE 0.1803368801111137f

// raw v_exp_f32 (2^x). exp2f() is a precise libcall -- 44% VALUBusy in r8.
#if __has_builtin(__builtin_amdgcn_exp2f)
#define EXP2(x) __builtin_amdgcn_exp2f(x)
#else
#define EXP2(x) __expf(0.6931471805599453f * (x))
#endif

__device__ __forceinline__ bf16x8 ld8(const bf16* p) { return *(const bf16x8*)p; }

// ------------- fp32 -> bf16 conversion of the 4 weight matrices ------------
__global__ __launch_bounds__(256) void cvt4_kernel(
    const float* __restrict__ w0, const float* __restrict__ w1,
    const float* __restrict__ w2, const float* __restrict__ w3,
    bf16* __restrict__ dst) {
  const float* srcs[4] = {w0, w1, w2, w3};
  const float* src = srcs[blockIdx.y];
  bf16* d = dst + (size_t)blockIdx.y * 262144;
  int i = (blockIdx.x * 256 + threadIdx.x) * 4;
  f32x4 v = *(const f32x4*)(src + i);
  bf16x4 o;
  for (int j = 0; j < 4; ++j) o[j] = (bf16)v[j];
  *(bf16x4*)(d + i) = o;
}

// ------------- q/k/v projection: double-buffered LDS, 1 barrier/iter ------
// C[128x128] per block, 4 waves 2x2 of 64x64, BK=64 (8 k-tiles).
// Coalesced staging (lanes -> consecutive 16B). q output pre-scaled QSCALE.
__global__ __launch_bounds__(256) void proj_gemm_kernel(
    const float* __restrict__ query, const float* __restrict__ kv,
    const bf16* __restrict__ Wall,
    const float* __restrict__ bq, const float* __restrict__ bk,
    const float* __restrict__ bv,
    bf16* __restrict__ qproj, bf16* __restrict__ kproj, bf16* __restrict__ vt) {
  __shared__ bf16 smA[2][128][72];
  __shared__ bf16 smB[2][128][72];
  const int tid = threadIdx.x;
  const int lane = tid & 63, wave = tid >> 6;
  const int lrow = lane & 15, quad = lane >> 4;
  const int wm = wave & 1, wn = wave >> 1;

  int x = blockIdx.x, z, mt;
  if (x < 32) { z = 0; mt = x; }
  else if (x < 96) { z = 1; mt = x - 32; }
  else { z = 2; mt = x - 96; }
  const float* A = ((z == 0) ? query : kv) + (size_t)mt * 128 * E;
  const bf16* W = Wall + (size_t)z * 262144;
  const float* bias = (z == 0) ? bq : (z == 1) ? bk : bv;
  const int n0 = blockIdx.y * 128;

  // A: row = p*16 + tid/16, 16B chunk = tid&15.  B: row = p*32+tid/8, chunk tid&7.
  const int arow = tid >> 4, acol = tid & 15;
  const int brow = tid >> 3, bcol = tid & 7;

  f32x4 pa[8];
  bf16x8 pb[4];
#define LOAD_T(t)                                                             \
  {                                                                           \
    for (int p = 0; p < 8; ++p)                                               \
      pa[p] = *(const f32x4*)(A + (size_t)(p * 16 + arow) * E + (t) * 64 +    \
                              acol * 4);                                      \
    for (int p = 0; p < 4; ++p)                                               \
      pb[p] = ld8(W + (size_t)(n0 + p * 32 + brow) * E + (t) * 64 + bcol * 8);\
  }
#define STORE_T(bs)                                                           \
  {                                                                           \
    for (int p = 0; p < 8; ++p) {                                             \
      bf16x4 av;                                                              \
      for (int e = 0; e < 4; ++e) av[e] = (bf16)pa[p][e];                     \
      *(bf16x4*)&smA[bs][p * 16 + arow][acol * 4] = av;                       \
    }                                                                         \
    for (int p = 0; p < 4; ++p)                                               \
      *(bf16x8*)&smB[bs][p * 32 + brow][bcol * 8] = pb[p];                    \
  }

  LOAD_T(0);
  STORE_T(0);
  LOAD_T(1);          // in flight across first compute
  __syncthreads();    // buf0 ready

  f32x4 acc[4][4] = {};
  for (int t = 0; t < 8; ++t) {
    const int bs = t & 1;
    bf16x8 af[2][4], bfr[2][4];
    for (int ks = 0; ks < 2; ++ks)
      for (int i = 0; i < 4; ++i)
        af[ks][i] = ld8(&smA[bs][wm * 64 + 16 * i + lrow][ks * 32 + quad * 8]);
    for (int ks = 0; ks < 2; ++ks)
      for (int c = 0; c < 4; ++c)
        bfr[ks][c] = ld8(&smB[bs][wn * 64 + 16 * c + lrow][ks * 32 + quad * 8]);
    for (int ks = 0; ks < 2; ++ks)
      for (int i = 0; i < 4; ++i)
        for (int c = 0; c < 4; ++c)
          acc[i][c] = MFMA16(af[ks][i], bfr[ks][c], acc[i][c]);
    if (t < 7) {
      STORE_T(bs ^ 1);          // tile t+1 into the other buffer
      if (t < 6) LOAD_T(t + 2); // distance-2 prefetch
    }
    __syncthreads();            // single barrier per iter
  }
#undef LOAD_T
#undef STORE_T

  const float qsc = (z == 0) ? QSCALE : 1.f;
  float bvl[4];
  for (int c = 0; c < 4; ++c) bvl[c] = bias[n0 + wn * 64 + 16 * c + lrow];
  bf16* Cs = &smA[0][0][0];  // reuse as [128][136] (17408 <= 18432 elems)
  for (int i = 0; i < 4; ++i)
    for (int c = 0; c < 4; ++c)
      for (int r = 0; r < 4; ++r) {
        int row = wm * 64 + 16 * i + 4 * quad + r;
        int col = wn * 64 + 16 * c + lrow;
        bf16 val = (bf16)((acc[i][c][r] + bvl[c]) * qsc);
        if (z < 2) Cs[row * 136 + col] = val;
        else       Cs[col * 136 + row] = val;
      }
  __syncthreads();
  const int rr = tid >> 1, hh = tid & 1;
  if (z < 2) {
    bf16* Y = (z == 0) ? qproj : kproj;
    bf16* dstp = Y + (size_t)(mt * 128 + rr) * E + n0 + hh * 64;
    for (int j = 0; j < 8; ++j)
      *(bf16x8*)(dstp + j * 8) = *(bf16x8*)&Cs[rr * 136 + hh * 64 + j * 8];
  } else {
    int m0g = mt * 128, b = m0g >> 12, kk0 = m0g & 4095;
    int ng = n0 + rr, hd = ng >> 6, d = ng & 63;
    bf16* dstp = vt + ((size_t)((b * 8 + hd) * 64 + d)) * LK + kk0 + hh * 64;
    for (int j = 0; j < 8; ++j)
      *(bf16x8*)(dstp + j * 8) = *(bf16x8*)&Cs[rr * 136 + hh * 64 + j * 8];
  }
}

// ---------------- fused flash attention (r6 structure, HW exp2) ------------
// 4 waves = 2 q-subtiles (32 q) x 2 kk-halves (2048 kk). LDS-staged K/V,
// double-buffered, 1 barrier/iter. Max-free softmax: p = v_exp_f32(st)
// (q pre-scaled by QSCALE). ctx written in-place over qproj.
// grid = 512 (2 blocks/CU), block 256.
__global__ __launch_bounds__(256, 2) void attn_kernel(
    const bf16* __restrict__ qp, const bf16* __restrict__ kp,
    const bf16* __restrict__ vtg, bf16* __restrict__ ctx) {
  const int tid = threadIdx.x;
  const int lane = tid & 63, wave = tid >> 6;
  const int lrow = lane & 15, quad = lane >> 4;
  const int blk = blockIdx.x;
  const int qt = blk & 31, bh = blk >> 5;
  const int b = bh >> 3, h = bh & 7;
  const int wq = wave & 1, half = wave >> 1;
  const int q0 = qt * 64 + wq * 32;

  __shared__ bf16 Ks[2][2][32][72];   // [half][dbuf][kk][d]
  __shared__ bf16 Vs[2][2][64][40];   // [half][dbuf][d][kk]
  __shared__ bf16 Ps[4][32][40];      // per-wave P [q][kk]
  __shared__ float Lr[2][2][16];      // half-1 row sums [wq][g][q]

  bf16x8 qf[2][2];  // [g][sd]; q pre-scaled by QSCALE
  for (int g = 0; g < 2; ++g)
    for (int s = 0; s < 2; ++s)
      qf[g][s] = ld8(qp + (size_t)(b * LQ + q0 + 16 * g + lrow) * E + h * DH +
                     32 * s + quad * 8);

  float lrun[2] = {0.f, 0.f};
  f32x4 acc[2][4] = {};

  const int th = tid & 127;
  const int krow = th >> 2, kch = th & 3;  // K: 32 kk-rows x 4 d-chunks
  const int vrow = th >> 1, vch = th & 1;  // V: 64 d-rows x 2 kk-chunks
  const bf16* kbase =
      kp + ((size_t)(b * LK) + half * 2048 + krow) * E + h * DH + kch * 16;
  const bf16* vbase =
      vtg + ((size_t)bh * DH + vrow) * LK + half * 2048 + vch * 16;

  bf16x8 pk0 = ld8(kbase), pk1 = ld8(kbase + 8);
  bf16x8 pv0 = ld8(vbase), pv1 = ld8(vbase + 8);

  for (int it = 0; it < 64; ++it) {
    const int bs = it & 1;
    *(bf16x8*)&Ks[half][bs][krow][kch * 16] = pk0;
    *(bf16x8*)&Ks[half][bs][krow][kch * 16 + 8] = pk1;
    *(bf16x8*)&Vs[half][bs][vrow][vch * 16] = pv0;
    *(bf16x8*)&Vs[half][bs][vrow][vch * 16 + 8] = pv1;
    __syncthreads();

    if (it < 63) {  // prefetch next 32-kk tile
      const bf16* kn = kbase + (size_t)(it + 1) * 32 * E;
      const bf16* vn = vbase + (it + 1) * 32;
      pk0 = ld8(kn); pk1 = ld8(kn + 8);
      pv0 = ld8(vn); pv1 = ld8(vn + 8);
    }

    bf16x8 kf[2][2], vf[4];
    for (int kt = 0; kt < 2; ++kt)
      for (int sd = 0; sd < 2; ++sd)
        kf[kt][sd] = ld8(&Ks[half][bs][16 * kt + lrow][32 * sd + quad * 8]);
    for (int c = 0; c < 4; ++c)
      vf[c] = ld8(&Vs[half][bs][16 * c + lrow][quad * 8]);

    // S^T = K Q^T: lane q = lrow (+16g), kk = 16kt + 4quad + r
    f32x4 st[2][2];
    for (int g = 0; g < 2; ++g)
      for (int kt = 0; kt < 2; ++kt) {
        st[g][kt] = (f32x4){0.f, 0.f, 0.f, 0.f};
        st[g][kt] = MFMA16(kf[kt][0], qf[g][0], st[g][kt]);
        st[g][kt] = MFMA16(kf[kt][1], qf[g][1], st[g][kt]);
      }
    for (int g = 0; g < 2; ++g)
      for (int kt = 0; kt < 2; ++kt) {
        bf16x4 pp;
        for (int r = 0; r < 4; ++r) {
          float p = EXP2(st[g][kt][r]);
          lrun[g] += p;
          pp[r] = (bf16)p;
        }
        *(bf16x4*)&Ps[wave][16 * g + lrow][16 * kt + 4 * quad] = pp;
      }
    // PV: A = P rows (q), k = kk 32; B = V^T rows (d)
    for (int g = 0; g < 2; ++g) {
      bf16x8 pf = ld8(&Ps[wave][16 * g + lrow][quad * 8]);
      for (int c = 0; c < 4; ++c)
        acc[g][c] = MFMA16(pf, vf[c], acc[g][c]);
    }
  }

  for (int g = 0; g < 2; ++g) {
    lrun[g] += __shfl_xor(lrun[g], 16);
    lrun[g] += __shfl_xor(lrun[g], 32);
  }

  // combine halves: half 1 publishes partial O + row sums, half 0 merges
  __syncthreads();
  float* F = (float*)&Ks[0][0][0][0];  // [2][32][65] floats
  if (half == 1) {
    for (int g = 0; g < 2; ++g)
      for (int c = 0; c < 4; ++c)
        for (int r = 0; r < 4; ++r)
          F[(wq * 32 + 16 * g + 4 * quad + r) * 65 + 16 * c + lrow] =
              acc[g][c][r];
    if (lane < 16)
      for (int g = 0; g < 2; ++g) Lr[wq][g][lrow] = lrun[g];
  }
  __syncthreads();
  if (half == 0) {
    for (int g = 0; g < 2; ++g)
      for (int r = 0; r < 4; ++r) {
        float l0 = __shfl(lrun[g], 4 * quad + r);
        float l1 = Lr[wq][g][4 * quad + r];
        float inv = 1.f / (l0 + l1);
        int m = q0 + 16 * g + 4 * quad + r;
        bf16* dst = ctx + (size_t)(b * LQ + m) * E + h * DH;
        for (int c = 0; c < 4; ++c) {
          float o = acc[g][c][r] +
                    F[(wq * 32 + 16 * g + 4 * quad + r) * 65 + 16 * c + lrow];
          dst[16 * c + lrow] = (bf16)(o * inv);
        }
      }
  }
}

// ------- out-proj + bias + residual + LayerNorm; Wo LDS-staged -------------
__global__ __launch_bounds__(512) void outln_kernel(
    const bf16* __restrict__ Cx, const bf16* __restrict__ Wo,
    const float* __restrict__ bo, const float* __restrict__ resid,
    const float* __restrict__ gamma, const float* __restrict__ beta,
    float* __restrict__ out) {
  const int tid = threadIdx.x;
  const int lane = tid & 63, wave = tid >> 6;
  const int lrow = lane & 15, quad = lane >> 4;
  const int m0 = blockIdx.x * 16;
  const int n0 = wave * 64;

  __shared__ bf16 As[16][520];
  __shared__ bf16 Wos[512][72];
  __shared__ float red1[16][8], red2[16][8];
  {
    int r = tid >> 5, ch = tid & 31;
    const bf16* src = Cx + (size_t)(m0 + r) * E + ch * 16;
    *(bf16x8*)&As[r][ch * 16] = ld8(src);
    *(bf16x8*)&As[r][ch * 16 + 8] = ld8(src + 8);
  }
  const int wr = tid >> 3, wc = tid & 7;
  bf16x8 pw[8];
  for (int p = 0; p < 8; ++p)
    pw[p] = ld8(Wo + (size_t)(p * 64 + wr) * E + wc * 8);
  __syncthreads();  // As ready

  f32x4 acc[4] = {};
  for (int t = 0; t < 8; ++t) {
    for (int p = 0; p < 8; ++p)
      *(bf16x8*)&Wos[p * 64 + wr][wc * 8] = pw[p];
    __syncthreads();
    if (t < 7)
      for (int p = 0; p < 8; ++p)
        pw[p] = ld8(Wo + (size_t)(p * 64 + wr) * E + (t + 1) * 64 + wc * 8);
    for (int ks = 0; ks < 2; ++ks) {
      bf16x8 a = *(const bf16x8*)&As[lrow][t * 64 + ks * 32 + quad * 8];
      for (int c = 0; c < 4; ++c) {
        bf16x8 w = *(const bf16x8*)&Wos[n0 + 16 * c + lrow][ks * 32 + quad * 8];
        acc[c] = MFMA16(a, w, acc[c]);
      }
    }
    __syncthreads();
  }

  float s1[4] = {}, s2[4] = {};
  for (int c = 0; c < 4; ++c) {
    int n = n0 + 16 * c + lrow;
    float bb = bo[n];
    for (int r = 0; r < 4; ++r) {
      int m = 4 * quad + r;
      float xv = acc[c][r] + bb + resid[(size_t)(m0 + m) * E + n];
      acc[c][r] = xv;
      s1[r] += xv;
      s2[r] += xv * xv;
    }
  }
  for (int off = 1; off < 16; off <<= 1)
    for (int r = 0; r < 4; ++r) {
      s1[r] += __shfl_xor(s1[r], off);
      s2[r] += __shfl_xor(s2[r], off);
    }
  if (lrow == 0)
    for (int r = 0; r < 4; ++r) {
      red1[4 * quad + r][wave] = s1[r];
      red2[4 * quad + r][wave] = s2[r];
    }
  __syncthreads();
  float mu[4], rstd[4];
  for (int r = 0; r < 4; ++r) {
    int m = 4 * quad + r;
    float t1 = 0.f, t2 = 0.f;
    for (int w = 0; w < 8; ++w) { t1 += red1[m][w]; t2 += red2[m][w]; }
    float mean = t1 * (1.f / 512.f);
    float var = t2 * (1.f / 512.f) - mean * mean;
    mu[r] = mean;
    rstd[r] = rsqrtf(var + 1e-5f);
  }
  for (int c = 0; c < 4; ++c) {
    int n = n0 + 16 * c + lrow;
    float gm = gamma[n], bt = beta[n];
    for (int r = 0; r < 4; ++r) {
      int m = m0 + 4 * quad + r;
      out[(size_t)m * E + n] = (acc[c][r] - mu[r]) * rstd[r] * gm + bt;
    }
  }
}

extern "C" void kernel_launch(void* const* d_in, const int* in_sizes, int n_in,
                              void* d_out, int out_size, void* d_ws, size_t ws_size,
                              hipStream_t stream) {
  const float* query     = (const float*)d_in[0];
  const float* key_value = (const float*)d_in[1];
  const float* Wq = (const float*)d_in[2];
  const float* bq = (const float*)d_in[3];
  const float* Wk = (const float*)d_in[4];
  const float* bk = (const float*)d_in[5];
  const float* Wv = (const float*)d_in[6];
  const float* bv = (const float*)d_in[7];
  const float* Wo = (const float*)d_in[8];
  const float* bo = (const float*)d_in[9];
  const float* gamma = (const float*)d_in[10];
  const float* beta  = (const float*)d_in[11];
  float* out = (float*)d_out;

  // ws layout (bf16): 4 weights | qproj(=ctx alias) | kproj | vt  (23 MB)
  bf16* Wb    = (bf16*)d_ws;
  bf16* Wob   = Wb + (size_t)3 * 262144;
  bf16* qproj = Wb + (size_t)4 * 262144;
  bf16* kproj = qproj + (size_t)4096 * 512;
  bf16* vt    = kproj + (size_t)8192 * 512;

  cvt4_kernel<<<dim3(256, 4), 256, 0, stream>>>(Wq, Wk, Wv, Wo, Wb);
  proj_gemm_kernel<<<dim3(160, 4), 256, 0, stream>>>(
      query, key_value, Wb, bq, bk, bv, qproj, kproj, vt);
  attn_kernel<<<512, 256, 0, stream>>>(qproj, kproj, vt, qproj /*ctx in-place*/);
  outln_kernel<<<256, 512, 0, stream>>>(qproj, Wob, bo, query, gamma, beta, out);
}